// Round 4
// baseline (3063.875 us; speedup 1.0000x reference)
//
#include <hip/hip_runtime.h>
#include <hip/hip_bf16.h>
#include <stdint.h>

typedef __hip_bfloat16 bf16;
typedef __bf16 bf16x8 __attribute__((ext_vector_type(8)));
typedef float floatx4 __attribute__((ext_vector_type(4)));

// ---------- dtype probe: *flag = 1 if x is fp32, 0 if bf16 ----------
// fp32 N(0,1) data: ~100% of words are finite with |v|<1e3.
// bf16 data read as fp32: exponent field comes from a bf16 exponent (~127)
// -> mostly |v|~1e38/inf/NaN -> ~5% pass. Threshold 50%.
__global__ void probe_dtype(const float* __restrict__ x, int* __restrict__ flag) {
    __shared__ int cnt;
    if (threadIdx.x == 0) cnt = 0;
    __syncthreads();
    int ok = 0;
    for (int i = threadIdx.x; i < 4096; i += 256) {
        float v = x[i];
        if (v == v && fabsf(v) < 1.0e3f) ok++;   // finite & sane
    }
    atomicAdd(&cnt, ok);
    __syncthreads();
    if (threadIdx.x == 0) *flag = (cnt > 2048) ? 1 : 0;
}

// ---------- convert raw (fp32 or bf16 per flag) -> canonical bf16 ----------
__global__ __launch_bounds__(256) void convert_to_bf16(
    const void* __restrict__ in, bf16* __restrict__ out, long n,
    const int* __restrict__ flag)
{
    long i = ((long)blockIdx.x * 256 + threadIdx.x) * 8;
    if (i >= n) return;
    bf16 o[8];
    if (*flag) {
        const float* p = (const float*)in + i;
        float4 a = *(const float4*)p;
        float4 b = *(const float4*)(p + 4);
        o[0] = __float2bfloat16(a.x); o[1] = __float2bfloat16(a.y);
        o[2] = __float2bfloat16(a.z); o[3] = __float2bfloat16(a.w);
        o[4] = __float2bfloat16(b.x); o[5] = __float2bfloat16(b.y);
        o[6] = __float2bfloat16(b.z); o[7] = __float2bfloat16(b.w);
    } else {
        *(float4*)o = *(const float4*)((const bf16*)in + i);
    }
    *(float4*)&out[i] = *(float4*)o;
}

// ---------- emit canonical bf16 -> d_out in flag dtype ----------
__global__ __launch_bounds__(256) void emit_out(
    const bf16* __restrict__ in, void* __restrict__ out, long n,
    const int* __restrict__ flag)
{
    long i = ((long)blockIdx.x * 256 + threadIdx.x) * 8;
    if (i >= n) return;
    bf16 v[8];
    *(float4*)v = *(const float4*)&in[i];
    if (*flag) {
        float* o = (float*)out + i;
        float4 a, b;
        a.x = __bfloat162float(v[0]); a.y = __bfloat162float(v[1]);
        a.z = __bfloat162float(v[2]); a.w = __bfloat162float(v[3]);
        b.x = __bfloat162float(v[4]); b.y = __bfloat162float(v[5]);
        b.z = __bfloat162float(v[6]); b.w = __bfloat162float(v[7]);
        *(float4*)o = a;
        *(float4*)(o + 4) = b;
    } else {
        *(float4*)((bf16*)out + i) = *(float4*)v;
    }
}

// ---------- transpose raw-dtype input -> bf16 output ----------
// out[c][r] = in[r][c] over 64x64 tiles. Dims multiples of 64. Offsets in
// ELEMENTS (dtype-agnostic).
__global__ __launch_bounds__(256) void transpose_any(
    const void* __restrict__ inv, bf16* __restrict__ out,
    int ldin, int ldout, const int* __restrict__ flag)
{
    __shared__ bf16 tile[64][80];
    const int fp32 = *flag;
    const int c0 = blockIdx.x * 64;
    const int r0 = blockIdx.y * 64;
    const int tid = threadIdx.x;
#pragma unroll
    for (int it = 0; it < 2; ++it) {
        int ch = tid + it * 256;
        int r = ch >> 3, c = (ch & 7) * 8;
        long eidx = (long)(r0 + r) * ldin + (c0 + c);
        if (fp32) {
            const float* p = (const float*)inv + eidx;
            float4 a = *(const float4*)p;
            float4 b = *(const float4*)(p + 4);
            bf16 o[8];
            o[0] = __float2bfloat16(a.x); o[1] = __float2bfloat16(a.y);
            o[2] = __float2bfloat16(a.z); o[3] = __float2bfloat16(a.w);
            o[4] = __float2bfloat16(b.x); o[5] = __float2bfloat16(b.y);
            o[6] = __float2bfloat16(b.z); o[7] = __float2bfloat16(b.w);
            *(float4*)&tile[r][c] = *(float4*)o;
        } else {
            *(float4*)&tile[r][c] = *(const float4*)((const bf16*)inv + eidx);
        }
    }
    __syncthreads();
#pragma unroll
    for (int it = 0; it < 2; ++it) {
        int ch = tid + it * 256;
        int oc = ch >> 3, rb = (ch & 7) * 8;
        bf16 tmp[8];
#pragma unroll
        for (int i = 0; i < 8; ++i) tmp[i] = tile[rb + i][oc];
        *(float4*)&out[(long)(c0 + oc) * ldout + r0 + rb] = *(float4*)tmp;
    }
}

// ---------- pure-bf16 transpose (workspace-internal, for V) ----------
__global__ __launch_bounds__(256) void transpose_bf16(
    const bf16* __restrict__ in, bf16* __restrict__ out,
    int ldin, int ldout,
    int nz1, long in_z1, long out_z1, long in_z2, long out_z2)
{
    __shared__ bf16 tile[64][80];
    const int z = blockIdx.z;
    const int z1 = z % nz1, z2 = z / nz1;
    in  += (long)z1 * in_z1 + (long)z2 * in_z2;
    out += (long)z1 * out_z1 + (long)z2 * out_z2;
    const int c0 = blockIdx.x * 64;
    const int r0 = blockIdx.y * 64;
    const int tid = threadIdx.x;
#pragma unroll
    for (int it = 0; it < 2; ++it) {
        int ch = tid + it * 256;
        int r = ch >> 3, c = (ch & 7) * 8;
        *(float4*)&tile[r][c] = *(const float4*)&in[(long)(r0 + r) * ldin + c0 + c];
    }
    __syncthreads();
#pragma unroll
    for (int it = 0; it < 2; ++it) {
        int ch = tid + it * 256;
        int oc = ch >> 3, rb = (ch & 7) * 8;
        bf16 tmp[8];
#pragma unroll
        for (int i = 0; i < 8; ++i) tmp[i] = tile[rb + i][oc];
        *(float4*)&out[(long)(c0 + oc) * ldout + r0 + rb] = *(float4*)tmp;
    }
}

// ---------- GEMM: C = (A * Bt^T + bias) * scale  (bf16 in/out, fp32 acc) ----
// accmode=1: C += A * Bt^T (reads existing C). Unchanged from round-3 audit.
__global__ __launch_bounds__(256) void gemm_bt(
    const bf16* __restrict__ A, const bf16* __restrict__ Bt,
    bf16* __restrict__ C, const bf16* __restrict__ bias,
    int lda, int ldb, int ldc,
    long az, long bz, long cz, int K, float scale, int accmode)
{
    __shared__ bf16 As[128 * 64];
    __shared__ bf16 Bs[128 * 64];

    const int tid  = threadIdx.x;
    const int lane = tid & 63;
    const int wave = tid >> 6;
    const int wx = wave & 1;
    const int wy = wave >> 1;
    const long zz = blockIdx.z;
    A  += zz * az;
    Bt += zz * bz;
    C  += zz * cz;
    const int m0 = blockIdx.y * 128;
    const int n0 = blockIdx.x * 128;

    const int lm = lane & 15;
    const int kq = (lane >> 4) * 8;

    floatx4 acc[4][4];
#pragma unroll
    for (int i = 0; i < 4; ++i)
#pragma unroll
        for (int j = 0; j < 4; ++j)
            acc[i][j] = (floatx4){0.f, 0.f, 0.f, 0.f};

    for (int kt = 0; kt < K; kt += 64) {
        float4 av[4], bv4[4];
#pragma unroll
        for (int it = 0; it < 4; ++it) {
            int ch = tid + it * 256;
            int r = ch >> 3;
            int c = (ch & 7) * 8;
            av[it]  = *(const float4*)&A [(long)(m0 + r) * lda + (kt + c)];
            bv4[it] = *(const float4*)&Bt[(long)(n0 + r) * ldb + (kt + c)];
        }
        __syncthreads();
#pragma unroll
        for (int it = 0; it < 4; ++it) {
            int ch = tid + it * 256;
            *(float4*)&As[ch * 8] = av[it];
            *(float4*)&Bs[ch * 8] = bv4[it];
        }
        __syncthreads();
#pragma unroll
        for (int kk = 0; kk < 64; kk += 32) {
            bf16x8 af[4], bfv[4];
#pragma unroll
            for (int i = 0; i < 4; ++i)
                af[i] = *(const bf16x8*)&As[(wy * 64 + i * 16 + lm) * 64 + kk + kq];
#pragma unroll
            for (int j = 0; j < 4; ++j)
                bfv[j] = *(const bf16x8*)&Bs[(wx * 64 + j * 16 + lm) * 64 + kk + kq];
#pragma unroll
            for (int i = 0; i < 4; ++i)
#pragma unroll
                for (int j = 0; j < 4; ++j)
                    acc[i][j] = __builtin_amdgcn_mfma_f32_16x16x32_bf16(
                        af[i], bfv[j], acc[i][j], 0, 0, 0);
        }
    }

    const int cr = (lane >> 4) * 4;
#pragma unroll
    for (int j = 0; j < 4; ++j) {
        int col = n0 + wx * 64 + j * 16 + lm;
        float bv = (!accmode && bias) ? __bfloat162float(bias[col]) : 0.f;
#pragma unroll
        for (int i = 0; i < 4; ++i) {
#pragma unroll
            for (int r = 0; r < 4; ++r) {
                int row = m0 + wy * 64 + i * 16 + cr + r;
                long idx = (long)row * ldc + col;
                float v;
                if (accmode) v = acc[i][j][r] + __bfloat162float(C[idx]);
                else         v = (acc[i][j][r] + bv) * scale;
                C[idx] = __float2bfloat16(v);
            }
        }
    }
}

// ---------- in-place softmax over rows of 2048 bf16 ----------
__global__ __launch_bounds__(256) void softmax_rows2048(bf16* __restrict__ S)
{
    __shared__ float red[8];
    const long row = blockIdx.x;
    bf16* p = S + row * 2048;
    const int tid = threadIdx.x;
    float4 raw = *(const float4*)&p[tid * 8];
    bf16 vb[8];
    *(float4*)vb = raw;
    float v[8];
#pragma unroll
    for (int i = 0; i < 8; ++i) v[i] = __bfloat162float(vb[i]);
    float m = v[0];
#pragma unroll
    for (int i = 1; i < 8; ++i) m = fmaxf(m, v[i]);
#pragma unroll
    for (int o = 32; o > 0; o >>= 1) m = fmaxf(m, __shfl_xor(m, o));
    if ((tid & 63) == 0) red[tid >> 6] = m;
    __syncthreads();
    m = fmaxf(fmaxf(red[0], red[1]), fmaxf(red[2], red[3]));
    float s = 0.f;
#pragma unroll
    for (int i = 0; i < 8; ++i) { v[i] = __expf(v[i] - m); s += v[i]; }
#pragma unroll
    for (int o = 32; o > 0; o >>= 1) s += __shfl_xor(s, o);
    if ((tid & 63) == 0) red[4 + (tid >> 6)] = s;
    __syncthreads();
    s = (red[4] + red[5]) + (red[6] + red[7]);
    float inv = 1.f / s;
#pragma unroll
    for (int i = 0; i < 8; ++i) vb[i] = __float2bfloat16(v[i] * inv);
    *(float4*)&p[tid * 8] = *(float4*)vb;
}

extern "C" void kernel_launch(void* const* d_in, const int* in_sizes, int n_in,
                              void* d_out, int out_size, void* d_ws, size_t ws_size,
                              hipStream_t stream)
{
    const int Bb = 4, T = 2048, E = 512, H = 8;
    const int HE = H * E;            // 4096
    const int M  = Bb * T;           // 8192
    const long NX = (long)M * E;     // 4,194,304 (x and out element count)

    // ---- size-signature input assignment (order-robust) ----
    const void* xr = nullptr;
    const void* Wr[4] = {nullptr, nullptr, nullptr, nullptr};  // Wq,Wk,Wv,Wo
    const void* br[3] = {nullptr, nullptr, nullptr};           // bq,bk,bv
    const void* bor = nullptr;
    int nw = 0, nb = 0;
    for (int i = 0; i < n_in; ++i) {
        int s = in_sizes[i];
        if      (s == (int)NX)      xr = d_in[i];
        else if (s == E * HE)       { if (nw < 4) Wr[nw++] = d_in[i]; }
        else if (s == HE)           { if (nb < 3) br[nb++] = d_in[i]; }
        else if (s == E)            bor = d_in[i];
    }
    if (!xr || nw < 4 || nb < 3 || !bor) {   // positional fallback
        xr = d_in[0]; Wr[0] = d_in[1]; br[0] = d_in[2]; Wr[1] = d_in[3];
        br[1] = d_in[4]; Wr[2] = d_in[5]; br[2] = d_in[6]; Wr[3] = d_in[7];
        bor = d_in[8];
    }

    const float qscale = 0.04419417382415922f;  // 1/sqrt(512)
    dim3 blk(256);

    // ---- workspace layout (bf16 elements; every offset multiple of 8) ----
    bf16* pool = (bf16*)d_ws;
    int*  flag = (int*)(void*)pool;     // first 16 B
    bf16* xc   = pool + 8;
    bf16* bqc  = xc  + NX;
    bf16* bkc  = bqc + HE;
    bf16* bvc  = bkc + HE;
    bf16* boc  = bvc + HE;
    bf16* WqT  = boc + E;               // padded: E=512 keeps alignment
    const size_t w2m = (size_t)E * HE;
    bf16* WkT  = WqT + w2m;
    bf16* WvT  = WkT + w2m;
    bf16* WoT  = WvT + w2m;
    bf16* Ofin = WoT + w2m;             // final pre-emit output, bf16 [M,E]
    bf16* p0   = Ofin + NX;             // tier region

    const size_t wsE   = ws_size / sizeof(bf16);
    const size_t fixedE = (size_t)(p0 - pool);
    const size_t wBat  = (size_t)T * HE;      // 8.39M
    const size_t wHd   = (size_t)T * E;       // 1.05M
    const size_t sAll  = (size_t)H * T * T;   // 33.55M
    const size_t sOne  = (size_t)T * T;       // 4.19M
    const size_t wBig  = (size_t)M * HE;      // 33.55M
    const size_t needA = fixedE + 4 * wBig + sAll;   // ~369 MB
    const size_t needB = fixedE + 5 * wBat + sAll;   // ~185 MB
    const size_t needC = fixedE + 5 * wBat + sOne;   // ~126 MB
    const size_t needD = fixedE + 5 * wHd  + sOne;   // ~53 MB
    if (wsE < needD) return;  // diagnostic: leaves d_out zeroed

    // ---- stage 0: dtype probe + canonicalize all inputs to bf16 ----
    probe_dtype<<<dim3(1), blk, 0, stream>>>((const float*)xr, flag);
    convert_to_bf16<<<dim3((unsigned)((NX / 8 + 255) / 256)), blk, 0, stream>>>(
        xr, xc, NX, flag);
    convert_to_bf16<<<dim3(2), blk, 0, stream>>>(br[0], bqc, HE, flag);
    convert_to_bf16<<<dim3(2), blk, 0, stream>>>(br[1], bkc, HE, flag);
    convert_to_bf16<<<dim3(2), blk, 0, stream>>>(br[2], bvc, HE, flag);
    convert_to_bf16<<<dim3(1), blk, 0, stream>>>(bor, boc, E, flag);
    transpose_any<<<dim3(HE / 64, E / 64, 1), blk, 0, stream>>>(Wr[0], WqT, HE, E, flag);
    transpose_any<<<dim3(HE / 64, E / 64, 1), blk, 0, stream>>>(Wr[1], WkT, HE, E, flag);
    transpose_any<<<dim3(HE / 64, E / 64, 1), blk, 0, stream>>>(Wr[2], WvT, HE, E, flag);
    transpose_any<<<dim3(E / 64, HE / 64, 1), blk, 0, stream>>>(Wr[3], WoT, E, HE, flag);

    // ---- tiered attention pipeline (canonical bf16) ----
    if (wsE >= needA) {
        bf16* Q  = p0;
        bf16* Kp = Q  + wBig;
        bf16* Vt = Kp + wBig;   // [b,h,e,t]
        bf16* O  = Vt + wBig;   // [b,t,h,e]
        bf16* VS = O  + wBig;   // V then S per batch

        gemm_bt<<<dim3(HE / 128, M / 128, 1), blk, 0, stream>>>(
            xc, WqT, Q, bqc, E, E, HE, 0, 0, 0, E, qscale, 0);
        gemm_bt<<<dim3(HE / 128, M / 128, 1), blk, 0, stream>>>(
            xc, WkT, Kp, bkc, E, E, HE, 0, 0, 0, E, 1.f, 0);
        gemm_bt<<<dim3(HE / 128, M / 128, 1), blk, 0, stream>>>(
            xc, WvT, VS, bvc, E, E, HE, 0, 0, 0, E, 1.f, 0);
        transpose_bf16<<<dim3(E / 64, T / 64, Bb * H), blk, 0, stream>>>(
            VS, Vt, HE, T, H, (long)E, (long)E * T, (long)T * HE, (long)H * E * T);
        for (int b = 0; b < Bb; ++b) {
            const size_t boff = (size_t)b * T * HE;
            gemm_bt<<<dim3(T / 128, T / 128, H), blk, 0, stream>>>(
                Q + boff, Kp + boff, VS, nullptr,
                HE, HE, T, (long)E, (long)E, (long)T * T, E, 1.f, 0);
            softmax_rows2048<<<dim3(H * T, 1, 1), blk, 0, stream>>>(VS);
            gemm_bt<<<dim3(E / 128, T / 128, H), blk, 0, stream>>>(
                VS, Vt + (size_t)b * H * E * T, O + boff, nullptr,
                T, T, HE, (long)T * T, (long)E * T, (long)E, T, 1.f, 0);
        }
        gemm_bt<<<dim3(E / 128, M / 128, 1), blk, 0, stream>>>(
            O, WoT, Ofin, boc, HE, HE, E, 0, 0, 0, HE, 1.f, 0);
    } else if (wsE >= needC) {
        const bool allHeads = (wsE >= needB);
        bf16* Qb  = p0;
        bf16* Kb  = Qb  + wBat;
        bf16* Vb  = Kb  + wBat;
        bf16* Vtb = Vb  + wBat;   // [h,e,t]
        bf16* Ob  = Vtb + wBat;   // [t,h,e]
        bf16* S   = Ob  + wBat;

        for (int b = 0; b < Bb; ++b) {
            const bf16* xb = xc + (size_t)b * T * E;
            gemm_bt<<<dim3(HE / 128, T / 128, 1), blk, 0, stream>>>(
                xb, WqT, Qb, bqc, E, E, HE, 0, 0, 0, E, qscale, 0);
            gemm_bt<<<dim3(HE / 128, T / 128, 1), blk, 0, stream>>>(
                xb, WkT, Kb, bkc, E, E, HE, 0, 0, 0, E, 1.f, 0);
            gemm_bt<<<dim3(HE / 128, T / 128, 1), blk, 0, stream>>>(
                xb, WvT, Vb, bvc, E, E, HE, 0, 0, 0, E, 1.f, 0);
            transpose_bf16<<<dim3(E / 64, T / 64, H), blk, 0, stream>>>(
                Vb, Vtb, HE, T, H, (long)E, (long)E * T, 0, 0);
            if (allHeads) {
                gemm_bt<<<dim3(T / 128, T / 128, H), blk, 0, stream>>>(
                    Qb, Kb, S, nullptr, HE, HE, T,
                    (long)E, (long)E, (long)T * T, E, 1.f, 0);
                softmax_rows2048<<<dim3(H * T, 1, 1), blk, 0, stream>>>(S);
                gemm_bt<<<dim3(E / 128, T / 128, H), blk, 0, stream>>>(
                    S, Vtb, Ob, nullptr, T, T, HE,
                    (long)T * T, (long)E * T, (long)E, T, 1.f, 0);
            } else {
                for (int h = 0; h < H; ++h) {
                    gemm_bt<<<dim3(T / 128, T / 128, 1), blk, 0, stream>>>(
                        Qb + (size_t)h * E, Kb + (size_t)h * E, S, nullptr,
                        HE, HE, T, 0, 0, 0, E, 1.f, 0);
                    softmax_rows2048<<<dim3(T, 1, 1), blk, 0, stream>>>(S);
                    gemm_bt<<<dim3(E / 128, T / 128, 1), blk, 0, stream>>>(
                        S, Vtb + (size_t)h * E * T, Ob + (size_t)h * E, nullptr,
                        T, T, HE, 0, 0, 0, T, 1.f, 0);
                }
            }
            gemm_bt<<<dim3(E / 128, T / 128, 1), blk, 0, stream>>>(
                Ob, WoT, Ofin + (size_t)b * T * E, boc,
                HE, HE, E, 0, 0, 0, HE, 1.f, 0);
        }
    } else {
        // Tier D: per-(batch,head); out-proj accumulates into Ofin
        bf16* Qh  = p0;
        bf16* Kh  = Qh  + wHd;
        bf16* Vh  = Kh  + wHd;
        bf16* Vth = Vh  + wHd;   // [e,t]
        bf16* Oh  = Vth + wHd;   // [t,e]
        bf16* S   = Oh  + wHd;

        for (int b = 0; b < Bb; ++b) {
            const bf16* xb = xc + (size_t)b * T * E;
            bf16* outb = Ofin + (size_t)b * T * E;
            for (int h = 0; h < H; ++h) {
                const size_t hw = (size_t)h * E * E;
                gemm_bt<<<dim3(E / 128, T / 128, 1), blk, 0, stream>>>(
                    xb, WqT + hw, Qh, bqc + (size_t)h * E, E, E, E,
                    0, 0, 0, E, qscale, 0);
                gemm_bt<<<dim3(E / 128, T / 128, 1), blk, 0, stream>>>(
                    xb, WkT + hw, Kh, bkc + (size_t)h * E, E, E, E,
                    0, 0, 0, E, 1.f, 0);
                gemm_bt<<<dim3(E / 128, T / 128, 1), blk, 0, stream>>>(
                    xb, WvT + hw, Vh, bvc + (size_t)h * E, E, E, E,
                    0, 0, 0, E, 1.f, 0);
                transpose_bf16<<<dim3(E / 64, T / 64, 1), blk, 0, stream>>>(
                    Vh, Vth, E, T, 1, 0, 0, 0, 0);
                gemm_bt<<<dim3(T / 128, T / 128, 1), blk, 0, stream>>>(
                    Qh, Kh, S, nullptr, E, E, T, 0, 0, 0, E, 1.f, 0);
                softmax_rows2048<<<dim3(T, 1, 1), blk, 0, stream>>>(S);
                gemm_bt<<<dim3(E / 128, T / 128, 1), blk, 0, stream>>>(
                    S, Vth, Oh, nullptr, T, T, E, 0, 0, 0, T, 1.f, 0);
                gemm_bt<<<dim3(E / 128, T / 128, 1), blk, 0, stream>>>(
                    Oh, WoT + (size_t)h * E, outb, (h == 0) ? boc : nullptr,
                    E, HE, E, 0, 0, 0, E, 1.f, (h == 0) ? 0 : 1);
            }
        }
    }

    // ---- emit in the probed dtype ----
    emit_out<<<dim3((unsigned)((NX / 8 + 255) / 256)), blk, 0, stream>>>(
        Ofin, d_out, NX, flag);
}

// Round 5
// 1168.053 us; speedup vs baseline: 2.6231x; 2.6231x over previous
//
#include <hip/hip_runtime.h>
#include <hip/hip_bf16.h>
#include <stdint.h>

typedef __hip_bfloat16 bf16;
typedef __bf16 bf16x8 __attribute__((ext_vector_type(8)));
typedef float floatx4 __attribute__((ext_vector_type(4)));

#define AS_LDS __attribute__((address_space(3)))
#define AS_GLB __attribute__((address_space(1)))

__device__ __forceinline__ void gload_lds16(const bf16* g, bf16* l) {
    __builtin_amdgcn_global_load_lds((const AS_GLB void*)g, (AS_LDS void*)l, 16, 0, 0);
}

// ---------- dtype probe: *flag = 1 if x is fp32, 0 if bf16 ----------
__global__ void probe_dtype(const float* __restrict__ x, int* __restrict__ flag) {
    __shared__ int cnt;
    if (threadIdx.x == 0) cnt = 0;
    __syncthreads();
    int ok = 0;
    for (int i = threadIdx.x; i < 4096; i += 256) {
        float v = x[i];
        if (v == v && fabsf(v) < 1.0e3f) ok++;
    }
    atomicAdd(&cnt, ok);
    __syncthreads();
    if (threadIdx.x == 0) *flag = (cnt > 2048) ? 1 : 0;
}

// ---------- convert raw (fp32 or bf16 per flag) -> canonical bf16 ----------
__global__ __launch_bounds__(256) void convert_to_bf16(
    const void* __restrict__ in, bf16* __restrict__ out, long n,
    const int* __restrict__ flag)
{
    long i = ((long)blockIdx.x * 256 + threadIdx.x) * 8;
    if (i >= n) return;
    bf16 o[8];
    if (*flag) {
        const float* p = (const float*)in + i;
        float4 a = *(const float4*)p;
        float4 b = *(const float4*)(p + 4);
        o[0] = __float2bfloat16(a.x); o[1] = __float2bfloat16(a.y);
        o[2] = __float2bfloat16(a.z); o[3] = __float2bfloat16(a.w);
        o[4] = __float2bfloat16(b.x); o[5] = __float2bfloat16(b.y);
        o[6] = __float2bfloat16(b.z); o[7] = __float2bfloat16(b.w);
    } else {
        *(float4*)o = *(const float4*)((const bf16*)in + i);
    }
    *(float4*)&out[i] = *(float4*)o;
}

// ---------- emit canonical bf16 -> d_out in flag dtype ----------
__global__ __launch_bounds__(256) void emit_out(
    const bf16* __restrict__ in, void* __restrict__ out, long n,
    const int* __restrict__ flag)
{
    long i = ((long)blockIdx.x * 256 + threadIdx.x) * 8;
    if (i >= n) return;
    bf16 v[8];
    *(float4*)v = *(const float4*)&in[i];
    if (*flag) {
        float* o = (float*)out + i;
        float4 a, b;
        a.x = __bfloat162float(v[0]); a.y = __bfloat162float(v[1]);
        a.z = __bfloat162float(v[2]); a.w = __bfloat162float(v[3]);
        b.x = __bfloat162float(v[4]); b.y = __bfloat162float(v[5]);
        b.z = __bfloat162float(v[6]); b.w = __bfloat162float(v[7]);
        *(float4*)o = a;
        *(float4*)(o + 4) = b;
    } else {
        *(float4*)((bf16*)out + i) = *(float4*)v;
    }
}

// ---------- transpose raw-dtype input -> bf16 output ----------
__global__ __launch_bounds__(256) void transpose_any(
    const void* __restrict__ inv, bf16* __restrict__ out,
    int ldin, int ldout, const int* __restrict__ flag)
{
    __shared__ bf16 tile[64][80];
    const int fp32 = *flag;
    const int c0 = blockIdx.x * 64;
    const int r0 = blockIdx.y * 64;
    const int tid = threadIdx.x;
#pragma unroll
    for (int it = 0; it < 2; ++it) {
        int ch = tid + it * 256;
        int r = ch >> 3, c = (ch & 7) * 8;
        long eidx = (long)(r0 + r) * ldin + (c0 + c);
        if (fp32) {
            const float* p = (const float*)inv + eidx;
            float4 a = *(const float4*)p;
            float4 b = *(const float4*)(p + 4);
            bf16 o[8];
            o[0] = __float2bfloat16(a.x); o[1] = __float2bfloat16(a.y);
            o[2] = __float2bfloat16(a.z); o[3] = __float2bfloat16(a.w);
            o[4] = __float2bfloat16(b.x); o[5] = __float2bfloat16(b.y);
            o[6] = __float2bfloat16(b.z); o[7] = __float2bfloat16(b.w);
            *(float4*)&tile[r][c] = *(float4*)o;
        } else {
            *(float4*)&tile[r][c] = *(const float4*)((const bf16*)inv + eidx);
        }
    }
    __syncthreads();
#pragma unroll
    for (int it = 0; it < 2; ++it) {
        int ch = tid + it * 256;
        int oc = ch >> 3, rb = (ch & 7) * 8;
        bf16 tmp[8];
#pragma unroll
        for (int i = 0; i < 8; ++i) tmp[i] = tile[rb + i][oc];
        *(float4*)&out[(long)(c0 + oc) * ldout + r0 + rb] = *(float4*)tmp;
    }
}

// ---------- pure-bf16 transpose (workspace-internal, for V) ----------
__global__ __launch_bounds__(256) void transpose_bf16(
    const bf16* __restrict__ in, bf16* __restrict__ out,
    int ldin, int ldout,
    int nz1, long in_z1, long out_z1, long in_z2, long out_z2)
{
    __shared__ bf16 tile[64][80];
    const int z = blockIdx.z;
    const int z1 = z % nz1, z2 = z / nz1;
    in  += (long)z1 * in_z1 + (long)z2 * in_z2;
    out += (long)z1 * out_z1 + (long)z2 * out_z2;
    const int c0 = blockIdx.x * 64;
    const int r0 = blockIdx.y * 64;
    const int tid = threadIdx.x;
#pragma unroll
    for (int it = 0; it < 2; ++it) {
        int ch = tid + it * 256;
        int r = ch >> 3, c = (ch & 7) * 8;
        *(float4*)&tile[r][c] = *(const float4*)&in[(long)(r0 + r) * ldin + c0 + c];
    }
    __syncthreads();
#pragma unroll
    for (int it = 0; it < 2; ++it) {
        int ch = tid + it * 256;
        int oc = ch >> 3, rb = (ch & 7) * 8;
        bf16 tmp[8];
#pragma unroll
        for (int i = 0; i < 8; ++i) tmp[i] = tile[rb + i][oc];
        *(float4*)&out[(long)(c0 + oc) * ldout + r0 + rb] = *(float4*)tmp;
    }
}

// ---------- GEMM: C = (A * Bt^T + bias) * scale  (bf16 in/out, fp32 acc) ----
// accmode=1: C += A * Bt^T. global_load_lds width-16 staging (m97 structure).
__global__ __launch_bounds__(256) void gemm_bt(
    const bf16* __restrict__ A, const bf16* __restrict__ Bt,
    bf16* __restrict__ C, const bf16* __restrict__ bias,
    int lda, int ldb, int ldc,
    long az, long bz, long cz, int K, float scale, int accmode)
{
    __shared__ bf16 As[128 * 64];
    __shared__ bf16 Bs[128 * 64];

    const int tid  = threadIdx.x;
    const int lane = tid & 63;
    const int wave = tid >> 6;
    const int wx = wave & 1;
    const int wy = wave >> 1;
    const long zz = blockIdx.z;
    A  += zz * az;
    Bt += zz * bz;
    C  += zz * cz;
    const int m0 = blockIdx.y * 128;
    const int n0 = blockIdx.x * 128;

    const int lm = lane & 15;
    const int kq = (lane >> 4) * 8;

    floatx4 acc[4][4];
#pragma unroll
    for (int i = 0; i < 4; ++i)
#pragma unroll
        for (int j = 0; j < 4; ++j)
            acc[i][j] = (floatx4){0.f, 0.f, 0.f, 0.f};

    for (int kt = 0; kt < K; kt += 64) {
        __syncthreads();   // all waves done reading previous tile
#pragma unroll
        for (int it = 0; it < 4; ++it) {
            int ch = tid + it * 256;     // 16B chunk id (wave-contiguous: DMA-safe)
            int r = ch >> 3;
            int c = (ch & 7) * 8;
            gload_lds16(A  + (long)(m0 + r) * lda + (kt + c), &As[ch * 8]);
            gload_lds16(Bt + (long)(n0 + r) * ldb + (kt + c), &Bs[ch * 8]);
        }
        __syncthreads();   // compiler drains vmcnt before s_barrier -> tile visible
#pragma unroll
        for (int kk = 0; kk < 64; kk += 32) {
            bf16x8 af[4], bfv[4];
#pragma unroll
            for (int i = 0; i < 4; ++i)
                af[i] = *(const bf16x8*)&As[(wy * 64 + i * 16 + lm) * 64 + kk + kq];
#pragma unroll
            for (int j = 0; j < 4; ++j)
                bfv[j] = *(const bf16x8*)&Bs[(wx * 64 + j * 16 + lm) * 64 + kk + kq];
#pragma unroll
            for (int i = 0; i < 4; ++i)
#pragma unroll
                for (int j = 0; j < 4; ++j)
                    acc[i][j] = __builtin_amdgcn_mfma_f32_16x16x32_bf16(
                        af[i], bfv[j], acc[i][j], 0, 0, 0);
        }
    }

    const int cr = (lane >> 4) * 4;
#pragma unroll
    for (int j = 0; j < 4; ++j) {
        int col = n0 + wx * 64 + j * 16 + lm;
        float bv = (!accmode && bias) ? __bfloat162float(bias[col]) : 0.f;
#pragma unroll
        for (int i = 0; i < 4; ++i) {
#pragma unroll
            for (int r = 0; r < 4; ++r) {
                int row = m0 + wy * 64 + i * 16 + cr + r;
                long idx = (long)row * ldc + col;
                float v;
                if (accmode) v = acc[i][j][r] + __bfloat162float(C[idx]);
                else         v = (acc[i][j][r] + bv) * scale;
                C[idx] = __float2bfloat16(v);
            }
        }
    }
}

// ---------- split-K GEMM: P[z][m][n] = A[m, zKc..] * Bt[n, zKc..]^T (fp32) ----
__global__ __launch_bounds__(256) void gemm_bt_splitk(
    const bf16* __restrict__ A, const bf16* __restrict__ Bt,
    float* __restrict__ P, int lda, int ldb, int M, int N, int Kc)
{
    __shared__ bf16 As[128 * 64];
    __shared__ bf16 Bs[128 * 64];

    const int tid  = threadIdx.x;
    const int lane = tid & 63;
    const int wave = tid >> 6;
    const int wx = wave & 1;
    const int wy = wave >> 1;
    const int m0 = blockIdx.y * 128;
    const int n0 = blockIdx.x * 128;
    const int k0 = blockIdx.z * Kc;

    const int lm = lane & 15;
    const int kq = (lane >> 4) * 8;

    floatx4 acc[4][4];
#pragma unroll
    for (int i = 0; i < 4; ++i)
#pragma unroll
        for (int j = 0; j < 4; ++j)
            acc[i][j] = (floatx4){0.f, 0.f, 0.f, 0.f};

    for (int kt = k0; kt < k0 + Kc; kt += 64) {
        __syncthreads();
#pragma unroll
        for (int it = 0; it < 4; ++it) {
            int ch = tid + it * 256;
            int r = ch >> 3;
            int c = (ch & 7) * 8;
            gload_lds16(A  + (long)(m0 + r) * lda + (kt + c), &As[ch * 8]);
            gload_lds16(Bt + (long)(n0 + r) * ldb + (kt + c), &Bs[ch * 8]);
        }
        __syncthreads();
#pragma unroll
        for (int kk = 0; kk < 64; kk += 32) {
            bf16x8 af[4], bfv[4];
#pragma unroll
            for (int i = 0; i < 4; ++i)
                af[i] = *(const bf16x8*)&As[(wy * 64 + i * 16 + lm) * 64 + kk + kq];
#pragma unroll
            for (int j = 0; j < 4; ++j)
                bfv[j] = *(const bf16x8*)&Bs[(wx * 64 + j * 16 + lm) * 64 + kk + kq];
#pragma unroll
            for (int i = 0; i < 4; ++i)
#pragma unroll
                for (int j = 0; j < 4; ++j)
                    acc[i][j] = __builtin_amdgcn_mfma_f32_16x16x32_bf16(
                        af[i], bfv[j], acc[i][j], 0, 0, 0);
        }
    }

    float* Pz = P + (long)blockIdx.z * M * N;
    const int cr = (lane >> 4) * 4;
#pragma unroll
    for (int j = 0; j < 4; ++j) {
        int col = n0 + wx * 64 + j * 16 + lm;
#pragma unroll
        for (int i = 0; i < 4; ++i)
#pragma unroll
            for (int r = 0; r < 4; ++r) {
                int row = m0 + wy * 64 + i * 16 + cr + r;
                Pz[(long)row * N + col] = acc[i][j][r];
            }
    }
}

// ---------- reduce split-K partials + bias -> bf16 ----------
__global__ __launch_bounds__(256) void reduce_splitk(
    const float* __restrict__ P, const bf16* __restrict__ bias,
    bf16* __restrict__ Out, long MN, int N, int SK)
{
    long i = (long)blockIdx.x * 256 + threadIdx.x;
    if (i >= MN) return;
    float s = bias ? __bfloat162float(bias[i & (N - 1)]) : 0.f;  // N power of 2
    for (int z = 0; z < SK; ++z) s += P[(long)z * MN + i];
    Out[i] = __float2bfloat16(s);
}

// ---------- in-place softmax over rows of 2048 bf16 ----------
__global__ __launch_bounds__(256) void softmax_rows2048(bf16* __restrict__ S)
{
    __shared__ float red[8];
    const long row = blockIdx.x;
    bf16* p = S + row * 2048;
    const int tid = threadIdx.x;
    float4 raw = *(const float4*)&p[tid * 8];
    bf16 vb[8];
    *(float4*)vb = raw;
    float v[8];
#pragma unroll
    for (int i = 0; i < 8; ++i) v[i] = __bfloat162float(vb[i]);
    float m = v[0];
#pragma unroll
    for (int i = 1; i < 8; ++i) m = fmaxf(m, v[i]);
#pragma unroll
    for (int o = 32; o > 0; o >>= 1) m = fmaxf(m, __shfl_xor(m, o));
    if ((tid & 63) == 0) red[tid >> 6] = m;
    __syncthreads();
    m = fmaxf(fmaxf(red[0], red[1]), fmaxf(red[2], red[3]));
    float s = 0.f;
#pragma unroll
    for (int i = 0; i < 8; ++i) { v[i] = __expf(v[i] - m); s += v[i]; }
#pragma unroll
    for (int o = 32; o > 0; o >>= 1) s += __shfl_xor(s, o);
    if ((tid & 63) == 0) red[4 + (tid >> 6)] = s;
    __syncthreads();
    s = (red[4] + red[5]) + (red[6] + red[7]);
    float inv = 1.f / s;
#pragma unroll
    for (int i = 0; i < 8; ++i) vb[i] = __float2bfloat16(v[i] * inv);
    *(float4*)&p[tid * 8] = *(float4*)vb;
}

extern "C" void kernel_launch(void* const* d_in, const int* in_sizes, int n_in,
                              void* d_out, int out_size, void* d_ws, size_t ws_size,
                              hipStream_t stream)
{
    const int Bb = 4, T = 2048, E = 512, H = 8;
    const int HE = H * E;            // 4096
    const int M  = Bb * T;           // 8192
    const long NX = (long)M * E;     // 4,194,304

    // ---- size-signature input assignment (order-robust; fixed the R2/3 NaN) ----
    const void* xr = nullptr;
    const void* Wr[4] = {nullptr, nullptr, nullptr, nullptr};
    const void* br[3] = {nullptr, nullptr, nullptr};
    const void* bor = nullptr;
    int nw = 0, nb = 0;
    for (int i = 0; i < n_in; ++i) {
        int s = in_sizes[i];
        if      (s == (int)NX)      xr = d_in[i];
        else if (s == E * HE)       { if (nw < 4) Wr[nw++] = d_in[i]; }
        else if (s == HE)           { if (nb < 3) br[nb++] = d_in[i]; }
        else if (s == E)            bor = d_in[i];
    }
    if (!xr || nw < 4 || nb < 3 || !bor) {
        xr = d_in[0]; Wr[0] = d_in[1]; br[0] = d_in[2]; Wr[1] = d_in[3];
        br[1] = d_in[4]; Wr[2] = d_in[5]; br[2] = d_in[6]; Wr[3] = d_in[7];
        bor = d_in[8];
    }

    const float qscale = 0.04419417382415922f;  // 1/sqrt(512)
    dim3 blk(256);

    // ---- workspace layout ----
    bf16* pool = (bf16*)d_ws;
    int*  flag = (int*)(void*)pool;
    bf16* xc   = pool + 8;
    bf16* bqc  = xc  + NX;
    bf16* bkc  = bqc + HE;
    bf16* bvc  = bkc + HE;
    bf16* boc  = bvc + HE;
    bf16* WqT  = boc + E;
    const size_t w2m = (size_t)E * HE;
    bf16* WkT  = WqT + w2m;
    bf16* WvT  = WkT + w2m;
    bf16* WoT  = WvT + w2m;
    bf16* Ofin = WoT + w2m;
    bf16* p0   = Ofin + NX;

    const size_t wsE    = ws_size / sizeof(bf16);
    const size_t fixedE = (size_t)(p0 - pool);
    const size_t wBat  = (size_t)T * HE;
    const size_t wHd   = (size_t)T * E;
    const size_t sAll  = (size_t)H * T * T;
    const size_t sOne  = (size_t)T * T;
    const size_t wBig  = (size_t)M * HE;
    const size_t needA = fixedE + 4 * wBig + sAll;
    const size_t needB = fixedE + 5 * wBat + sAll;
    const size_t needC = fixedE + 5 * wBat + sOne;
    const size_t needD = fixedE + 5 * wHd  + sOne;
    if (wsE < needD) return;

    // ---- stage 0: dtype probe + canonicalize ----
    probe_dtype<<<dim3(1), blk, 0, stream>>>((const float*)xr, flag);
    convert_to_bf16<<<dim3((unsigned)((NX / 8 + 255) / 256)), blk, 0, stream>>>(
        xr, xc, NX, flag);
    convert_to_bf16<<<dim3(2), blk, 0, stream>>>(br[0], bqc, HE, flag);
    convert_to_bf16<<<dim3(2), blk, 0, stream>>>(br[1], bkc, HE, flag);
    convert_to_bf16<<<dim3(2), blk, 0, stream>>>(br[2], bvc, HE, flag);
    convert_to_bf16<<<dim3(1), blk, 0, stream>>>(bor, boc, E, flag);
    transpose_any<<<dim3(HE / 64, E / 64, 1), blk, 0, stream>>>(Wr[0], WqT, HE, E, flag);
    transpose_any<<<dim3(HE / 64, E / 64, 1), blk, 0, stream>>>(Wr[1], WkT, HE, E, flag);
    transpose_any<<<dim3(HE / 64, E / 64, 1), blk, 0, stream>>>(Wr[2], WvT, HE, E, flag);
    transpose_any<<<dim3(E / 64, HE / 64, 1), blk, 0, stream>>>(Wr[3], WoT, E, HE, flag);

    if (wsE >= needA) {
        // ---- Tier A ----
        bf16* Q  = p0;
        bf16* Kp = Q  + wBig;
        bf16* Vt = Kp + wBig;
        bf16* O  = Vt + wBig;
        bf16* VS = O  + wBig;

        gemm_bt<<<dim3(HE / 128, M / 128, 1), blk, 0, stream>>>(
            xc, WqT, Q, bqc, E, E, HE, 0, 0, 0, E, qscale, 0);
        gemm_bt<<<dim3(HE / 128, M / 128, 1), blk, 0, stream>>>(
            xc, WkT, Kp, bkc, E, E, HE, 0, 0, 0, E, 1.f, 0);
        gemm_bt<<<dim3(HE / 128, M / 128, 1), blk, 0, stream>>>(
            xc, WvT, VS, bvc, E, E, HE, 0, 0, 0, E, 1.f, 0);
        transpose_bf16<<<dim3(E / 64, T / 64, Bb * H), blk, 0, stream>>>(
            VS, Vt, HE, T, H, (long)E, (long)E * T, (long)T * HE, (long)H * E * T);
        for (int b = 0; b < Bb; ++b) {
            const size_t boff = (size_t)b * T * HE;
            gemm_bt<<<dim3(T / 128, T / 128, H), blk, 0, stream>>>(
                Q + boff, Kp + boff, VS, nullptr,
                HE, HE, T, (long)E, (long)E, (long)T * T, E, 1.f, 0);
            softmax_rows2048<<<dim3(H * T, 1, 1), blk, 0, stream>>>(VS);
            gemm_bt<<<dim3(E / 128, T / 128, H), blk, 0, stream>>>(
                VS, Vt + (size_t)b * H * E * T, O + boff, nullptr,
                T, T, HE, (long)T * T, (long)E * T, (long)E, T, 1.f, 0);
        }
        gemm_bt<<<dim3(E / 128, M / 128, 1), blk, 0, stream>>>(
            O, WoT, Ofin, boc, HE, HE, E, 0, 0, 0, HE, 1.f, 0);
    } else if (wsE >= needC) {
        // ---- Tier B/C (B is what runs at the observed ws_size) ----
        const bool allHeads = (wsE >= needB);
        bf16* Qb  = p0;
        bf16* Kb  = Qb  + wBat;
        bf16* Vb  = Kb  + wBat;
        bf16* Vtb = Vb  + wBat;
        bf16* Ob  = Vtb + wBat;
        bf16* S   = Ob  + wBat;

        for (int b = 0; b < Bb; ++b) {
            const bf16* xb = xc + (size_t)b * T * E;
            gemm_bt<<<dim3(HE / 128, T / 128, 1), blk, 0, stream>>>(
                xb, WqT, Qb, bqc, E, E, HE, 0, 0, 0, E, qscale, 0);
            gemm_bt<<<dim3(HE / 128, T / 128, 1), blk, 0, stream>>>(
                xb, WkT, Kb, bkc, E, E, HE, 0, 0, 0, E, 1.f, 0);
            gemm_bt<<<dim3(HE / 128, T / 128, 1), blk, 0, stream>>>(
                xb, WvT, Vb, bvc, E, E, HE, 0, 0, 0, E, 1.f, 0);
            transpose_bf16<<<dim3(E / 64, T / 64, H), blk, 0, stream>>>(
                Vb, Vtb, HE, T, H, (long)E, (long)E * T, 0, 0);
            if (allHeads) {
                gemm_bt<<<dim3(T / 128, T / 128, H), blk, 0, stream>>>(
                    Qb, Kb, S, nullptr, HE, HE, T,
                    (long)E, (long)E, (long)T * T, E, 1.f, 0);
                softmax_rows2048<<<dim3(H * T, 1, 1), blk, 0, stream>>>(S);
                gemm_bt<<<dim3(E / 128, T / 128, H), blk, 0, stream>>>(
                    S, Vtb, Ob, nullptr, T, T, HE,
                    (long)T * T, (long)E * T, (long)E, T, 1.f, 0);
            } else {
                for (int h = 0; h < H; ++h) {
                    gemm_bt<<<dim3(T / 128, T / 128, 1), blk, 0, stream>>>(
                        Qb + (size_t)h * E, Kb + (size_t)h * E, S, nullptr,
                        HE, HE, T, 0, 0, 0, E, 1.f, 0);
                    softmax_rows2048<<<dim3(T, 1, 1), blk, 0, stream>>>(S);
                    gemm_bt<<<dim3(E / 128, T / 128, 1), blk, 0, stream>>>(
                        S, Vtb + (size_t)h * E * T, Ob + (size_t)h * E, nullptr,
                        T, T, HE, 0, 0, 0, T, 1.f, 0);
                }
            }
            // Output projection: split-K=8 (fp32 partials alias S, idle here),
            // grid 512 blocks instead of 64 -> kills the 201us low-occupancy tail.
            gemm_bt_splitk<<<dim3(E / 128, T / 128, 8), blk, 0, stream>>>(
                Ob, WoT, (float*)S, HE, HE, T, E, HE / 8);
            reduce_splitk<<<dim3((unsigned)(((long)T * E + 255) / 256)), blk, 0, stream>>>(
                (float*)S, boc, Ofin + (size_t)b * T * E, (long)T * E, E, 8);
        }
    } else {
        // ---- Tier D ----
        bf16* Qh  = p0;
        bf16* Kh  = Qh  + wHd;
        bf16* Vh  = Kh  + wHd;
        bf16* Vth = Vh  + wHd;
        bf16* Oh  = Vth + wHd;
        bf16* S   = Oh  + wHd;

        for (int b = 0; b < Bb; ++b) {
            const bf16* xb = xc + (size_t)b * T * E;
            bf16* outb = Ofin + (size_t)b * T * E;
            for (int h = 0; h < H; ++h) {
                const size_t hw = (size_t)h * E * E;
                gemm_bt<<<dim3(E / 128, T / 128, 1), blk, 0, stream>>>(
                    xb, WqT + hw, Qh, bqc + (size_t)h * E, E, E, E,
                    0, 0, 0, E, qscale, 0);
                gemm_bt<<<dim3(E / 128, T / 128, 1), blk, 0, stream>>>(
                    xb, WkT + hw, Kh, bkc + (size_t)h * E, E, E, E,
                    0, 0, 0, E, 1.f, 0);
                gemm_bt<<<dim3(E / 128, T / 128, 1), blk, 0, stream>>>(
                    xb, WvT + hw, Vh, bvc + (size_t)h * E, E, E, E,
                    0, 0, 0, E, 1.f, 0);
                transpose_bf16<<<dim3(E / 64, T / 64, 1), blk, 0, stream>>>(
                    Vh, Vth, E, T, 1, 0, 0, 0, 0);
                gemm_bt<<<dim3(T / 128, T / 128, 1), blk, 0, stream>>>(
                    Qh, Kh, S, nullptr, E, E, T, 0, 0, 0, E, 1.f, 0);
                softmax_rows2048<<<dim3(T, 1, 1), blk, 0, stream>>>(S);
                gemm_bt<<<dim3(E / 128, T / 128, 1), blk, 0, stream>>>(
                    S, Vth, Oh, nullptr, T, T, E, 0, 0, 0, T, 1.f, 0);
                gemm_bt<<<dim3(E / 128, T / 128, 1), blk, 0, stream>>>(
                    Oh, WoT + (size_t)h * E, outb, (h == 0) ? boc : nullptr,
                    E, HE, E, 0, 0, 0, E, 1.f, (h == 0) ? 0 : 1);
            }
        }
    }

    // ---- emit in the probed dtype ----
    emit_out<<<dim3((unsigned)((NX / 8 + 255) / 256)), blk, 0, stream>>>(
        Ofin, d_out, NX, flag);
}

// Round 6
// 1129.612 us; speedup vs baseline: 2.7123x; 1.0340x over previous
//
#include <hip/hip_runtime.h>
#include <hip/hip_bf16.h>
#include <stdint.h>

typedef __hip_bfloat16 bf16;
typedef __bf16 bf16x8 __attribute__((ext_vector_type(8)));
typedef float floatx4 __attribute__((ext_vector_type(4)));

#define AS_LDS __attribute__((address_space(3)))
#define AS_GLB __attribute__((address_space(1)))

__device__ __forceinline__ void gload_lds16(const bf16* g, bf16* l) {
    __builtin_amdgcn_global_load_lds((const AS_GLB void*)g, (AS_LDS void*)l, 16, 0, 0);
}

// ---------- dtype probe: *flag = 1 if x is fp32, 0 if bf16 ----------
__global__ void probe_dtype(const float* __restrict__ x, int* __restrict__ flag) {
    __shared__ int cnt;
    if (threadIdx.x == 0) cnt = 0;
    __syncthreads();
    int ok = 0;
    for (int i = threadIdx.x; i < 4096; i += 256) {
        float v = x[i];
        if (v == v && fabsf(v) < 1.0e3f) ok++;
    }
    atomicAdd(&cnt, ok);
    __syncthreads();
    if (threadIdx.x == 0) *flag = (cnt > 2048) ? 1 : 0;
}

// ---------- convert raw (fp32 or bf16 per flag) -> canonical bf16 ----------
__global__ __launch_bounds__(256) void convert_to_bf16(
    const void* __restrict__ in, bf16* __restrict__ out, long n,
    const int* __restrict__ flag)
{
    long i = ((long)blockIdx.x * 256 + threadIdx.x) * 8;
    if (i >= n) return;
    bf16 o[8];
    if (*flag) {
        const float* p = (const float*)in + i;
        float4 a = *(const float4*)p;
        float4 b = *(const float4*)(p + 4);
        o[0] = __float2bfloat16(a.x); o[1] = __float2bfloat16(a.y);
        o[2] = __float2bfloat16(a.z); o[3] = __float2bfloat16(a.w);
        o[4] = __float2bfloat16(b.x); o[5] = __float2bfloat16(b.y);
        o[6] = __float2bfloat16(b.z); o[7] = __float2bfloat16(b.w);
    } else {
        *(float4*)o = *(const float4*)((const bf16*)in + i);
    }
    *(float4*)&out[i] = *(float4*)o;
}

// ---------- emit canonical bf16 -> d_out in flag dtype ----------
__global__ __launch_bounds__(256) void emit_out(
    const bf16* __restrict__ in, void* __restrict__ out, long n,
    const int* __restrict__ flag)
{
    long i = ((long)blockIdx.x * 256 + threadIdx.x) * 8;
    if (i >= n) return;
    bf16 v[8];
    *(float4*)v = *(const float4*)&in[i];
    if (*flag) {
        float* o = (float*)out + i;
        float4 a, b;
        a.x = __bfloat162float(v[0]); a.y = __bfloat162float(v[1]);
        a.z = __bfloat162float(v[2]); a.w = __bfloat162float(v[3]);
        b.x = __bfloat162float(v[4]); b.y = __bfloat162float(v[5]);
        b.z = __bfloat162float(v[6]); b.w = __bfloat162float(v[7]);
        *(float4*)o = a;
        *(float4*)(o + 4) = b;
    } else {
        *(float4*)((bf16*)out + i) = *(float4*)v;
    }
}

// ---------- transpose raw-dtype input -> bf16 output ----------
__global__ __launch_bounds__(256) void transpose_any(
    const void* __restrict__ inv, bf16* __restrict__ out,
    int ldin, int ldout, const int* __restrict__ flag)
{
    __shared__ bf16 tile[64][80];
    const int fp32 = *flag;
    const int c0 = blockIdx.x * 64;
    const int r0 = blockIdx.y * 64;
    const int tid = threadIdx.x;
#pragma unroll
    for (int it = 0; it < 2; ++it) {
        int ch = tid + it * 256;
        int r = ch >> 3, c = (ch & 7) * 8;
        long eidx = (long)(r0 + r) * ldin + (c0 + c);
        if (fp32) {
            const float* p = (const float*)inv + eidx;
            float4 a = *(const float4*)p;
            float4 b = *(const float4*)(p + 4);
            bf16 o[8];
            o[0] = __float2bfloat16(a.x); o[1] = __float2bfloat16(a.y);
            o[2] = __float2bfloat16(a.z); o[3] = __float2bfloat16(a.w);
            o[4] = __float2bfloat16(b.x); o[5] = __float2bfloat16(b.y);
            o[6] = __float2bfloat16(b.z); o[7] = __float2bfloat16(b.w);
            *(float4*)&tile[r][c] = *(float4*)o;
        } else {
            *(float4*)&tile[r][c] = *(const float4*)((const bf16*)inv + eidx);
        }
    }
    __syncthreads();
#pragma unroll
    for (int it = 0; it < 2; ++it) {
        int ch = tid + it * 256;
        int oc = ch >> 3, rb = (ch & 7) * 8;
        bf16 tmp[8];
#pragma unroll
        for (int i = 0; i < 8; ++i) tmp[i] = tile[rb + i][oc];
        *(float4*)&out[(long)(c0 + oc) * ldout + r0 + rb] = *(float4*)tmp;
    }
}

// ---------- pure-bf16 transpose (workspace-internal, for V) ----------
__global__ __launch_bounds__(256) void transpose_bf16(
    const bf16* __restrict__ in, bf16* __restrict__ out,
    int ldin, int ldout,
    int nz1, long in_z1, long out_z1, long in_z2, long out_z2)
{
    __shared__ bf16 tile[64][80];
    const int z = blockIdx.z;
    const int z1 = z % nz1, z2 = z / nz1;
    in  += (long)z1 * in_z1 + (long)z2 * in_z2;
    out += (long)z1 * out_z1 + (long)z2 * out_z2;
    const int c0 = blockIdx.x * 64;
    const int r0 = blockIdx.y * 64;
    const int tid = threadIdx.x;
#pragma unroll
    for (int it = 0; it < 2; ++it) {
        int ch = tid + it * 256;
        int r = ch >> 3, c = (ch & 7) * 8;
        *(float4*)&tile[r][c] = *(const float4*)&in[(long)(r0 + r) * ldin + c0 + c];
    }
    __syncthreads();
#pragma unroll
    for (int it = 0; it < 2; ++it) {
        int ch = tid + it * 256;
        int oc = ch >> 3, rb = (ch & 7) * 8;
        bf16 tmp[8];
#pragma unroll
        for (int i = 0; i < 8; ++i) tmp[i] = tile[rb + i][oc];
        *(float4*)&out[(long)(c0 + oc) * ldout + r0 + rb] = *(float4*)tmp;
    }
}

// ---------- GEMM: C = (A * Bt^T + bias) * sc  (bf16 in/out, fp32 acc) -------
// sc = scale when col < qcols else 1 (lets one dispatch compute Q|K|V with
// qscale on the Q columns only). accmode=1: C += A * Bt^T.
__global__ __launch_bounds__(256) void gemm_bt(
    const bf16* __restrict__ A, const bf16* __restrict__ Bt,
    bf16* __restrict__ C, const bf16* __restrict__ bias,
    int lda, int ldb, int ldc,
    long az, long bz, long cz, int K, float scale, int qcols, int accmode)
{
    __shared__ bf16 As[128 * 64];
    __shared__ bf16 Bs[128 * 64];

    const int tid  = threadIdx.x;
    const int lane = tid & 63;
    const int wave = tid >> 6;
    const int wx = wave & 1;
    const int wy = wave >> 1;
    const long zz = blockIdx.z;
    A  += zz * az;
    Bt += zz * bz;
    C  += zz * cz;
    const int m0 = blockIdx.y * 128;
    const int n0 = blockIdx.x * 128;

    const int lm = lane & 15;
    const int kq = (lane >> 4) * 8;

    floatx4 acc[4][4];
#pragma unroll
    for (int i = 0; i < 4; ++i)
#pragma unroll
        for (int j = 0; j < 4; ++j)
            acc[i][j] = (floatx4){0.f, 0.f, 0.f, 0.f};

    for (int kt = 0; kt < K; kt += 64) {
        __syncthreads();
#pragma unroll
        for (int it = 0; it < 4; ++it) {
            int ch = tid + it * 256;
            int r = ch >> 3;
            int c = (ch & 7) * 8;
            gload_lds16(A  + (long)(m0 + r) * lda + (kt + c), &As[ch * 8]);
            gload_lds16(Bt + (long)(n0 + r) * ldb + (kt + c), &Bs[ch * 8]);
        }
        __syncthreads();
#pragma unroll
        for (int kk = 0; kk < 64; kk += 32) {
            bf16x8 af[4], bfv[4];
#pragma unroll
            for (int i = 0; i < 4; ++i)
                af[i] = *(const bf16x8*)&As[(wy * 64 + i * 16 + lm) * 64 + kk + kq];
#pragma unroll
            for (int j = 0; j < 4; ++j)
                bfv[j] = *(const bf16x8*)&Bs[(wx * 64 + j * 16 + lm) * 64 + kk + kq];
#pragma unroll
            for (int i = 0; i < 4; ++i)
#pragma unroll
                for (int j = 0; j < 4; ++j)
                    acc[i][j] = __builtin_amdgcn_mfma_f32_16x16x32_bf16(
                        af[i], bfv[j], acc[i][j], 0, 0, 0);
        }
    }

    const int cr = (lane >> 4) * 4;
#pragma unroll
    for (int j = 0; j < 4; ++j) {
        int col = n0 + wx * 64 + j * 16 + lm;
        float bv = (!accmode && bias) ? __bfloat162float(bias[col]) : 0.f;
        float sc = (col < qcols) ? scale : 1.0f;
#pragma unroll
        for (int i = 0; i < 4; ++i) {
#pragma unroll
            for (int r = 0; r < 4; ++r) {
                int row = m0 + wy * 64 + i * 16 + cr + r;
                long idx = (long)row * ldc + col;
                float v;
                if (accmode) v = acc[i][j][r] + __bfloat162float(C[idx]);
                else         v = (acc[i][j][r] + bv) * sc;
                C[idx] = __float2bfloat16(v);
            }
        }
    }
}

// ---------- split-K GEMM: P[z][m][n] = A[m, zKc..] * Bt[n, zKc..]^T (fp32) ----
__global__ __launch_bounds__(256) void gemm_bt_splitk(
    const bf16* __restrict__ A, const bf16* __restrict__ Bt,
    float* __restrict__ P, int lda, int ldb, int M, int N, int Kc)
{
    __shared__ bf16 As[128 * 64];
    __shared__ bf16 Bs[128 * 64];

    const int tid  = threadIdx.x;
    const int lane = tid & 63;
    const int wave = tid >> 6;
    const int wx = wave & 1;
    const int wy = wave >> 1;
    const int m0 = blockIdx.y * 128;
    const int n0 = blockIdx.x * 128;
    const int k0 = blockIdx.z * Kc;

    const int lm = lane & 15;
    const int kq = (lane >> 4) * 8;

    floatx4 acc[4][4];
#pragma unroll
    for (int i = 0; i < 4; ++i)
#pragma unroll
        for (int j = 0; j < 4; ++j)
            acc[i][j] = (floatx4){0.f, 0.f, 0.f, 0.f};

    for (int kt = k0; kt < k0 + Kc; kt += 64) {
        __syncthreads();
#pragma unroll
        for (int it = 0; it < 4; ++it) {
            int ch = tid + it * 256;
            int r = ch >> 3;
            int c = (ch & 7) * 8;
            gload_lds16(A  + (long)(m0 + r) * lda + (kt + c), &As[ch * 8]);
            gload_lds16(Bt + (long)(n0 + r) * ldb + (kt + c), &Bs[ch * 8]);
        }
        __syncthreads();
#pragma unroll
        for (int kk = 0; kk < 64; kk += 32) {
            bf16x8 af[4], bfv[4];
#pragma unroll
            for (int i = 0; i < 4; ++i)
                af[i] = *(const bf16x8*)&As[(wy * 64 + i * 16 + lm) * 64 + kk + kq];
#pragma unroll
            for (int j = 0; j < 4; ++j)
                bfv[j] = *(const bf16x8*)&Bs[(wx * 64 + j * 16 + lm) * 64 + kk + kq];
#pragma unroll
            for (int i = 0; i < 4; ++i)
#pragma unroll
                for (int j = 0; j < 4; ++j)
                    acc[i][j] = __builtin_amdgcn_mfma_f32_16x16x32_bf16(
                        af[i], bfv[j], acc[i][j], 0, 0, 0);
        }
    }

    float* Pz = P + (long)blockIdx.z * M * N;
    const int cr = (lane >> 4) * 4;
#pragma unroll
    for (int j = 0; j < 4; ++j) {
        int col = n0 + wx * 64 + j * 16 + lm;
#pragma unroll
        for (int i = 0; i < 4; ++i)
#pragma unroll
            for (int r = 0; r < 4; ++r) {
                int row = m0 + wy * 64 + i * 16 + cr + r;
                Pz[(long)row * N + col] = acc[i][j][r];
            }
    }
}

// ---------- reduce split-K partials + bias -> bf16 ----------
__global__ __launch_bounds__(256) void reduce_splitk(
    const float* __restrict__ P, const bf16* __restrict__ bias,
    bf16* __restrict__ Out, long MN, int N, int SK)
{
    long i = (long)blockIdx.x * 256 + threadIdx.x;
    if (i >= MN) return;
    float s = bias ? __bfloat162float(bias[i & (N - 1)]) : 0.f;  // N power of 2
    for (int z = 0; z < SK; ++z) s += P[(long)z * MN + i];
    Out[i] = __float2bfloat16(s);
}

// ---------- in-place softmax over rows of 2048 bf16 ----------
__global__ __launch_bounds__(256) void softmax_rows2048(bf16* __restrict__ S)
{
    __shared__ float red[8];
    const long row = blockIdx.x;
    bf16* p = S + row * 2048;
    const int tid = threadIdx.x;
    float4 raw = *(const float4*)&p[tid * 8];
    bf16 vb[8];
    *(float4*)vb = raw;
    float v[8];
#pragma unroll
    for (int i = 0; i < 8; ++i) v[i] = __bfloat162float(vb[i]);
    float m = v[0];
#pragma unroll
    for (int i = 1; i < 8; ++i) m = fmaxf(m, v[i]);
#pragma unroll
    for (int o = 32; o > 0; o >>= 1) m = fmaxf(m, __shfl_xor(m, o));
    if ((tid & 63) == 0) red[tid >> 6] = m;
    __syncthreads();
    m = fmaxf(fmaxf(red[0], red[1]), fmaxf(red[2], red[3]));
    float s = 0.f;
#pragma unroll
    for (int i = 0; i < 8; ++i) { v[i] = __expf(v[i] - m); s += v[i]; }
#pragma unroll
    for (int o = 32; o > 0; o >>= 1) s += __shfl_xor(s, o);
    if ((tid & 63) == 0) red[4 + (tid >> 6)] = s;
    __syncthreads();
    s = (red[4] + red[5]) + (red[6] + red[7]);
    float inv = 1.f / s;
#pragma unroll
    for (int i = 0; i < 8; ++i) vb[i] = __float2bfloat16(v[i] * inv);
    *(float4*)&p[tid * 8] = *(float4*)vb;
}

extern "C" void kernel_launch(void* const* d_in, const int* in_sizes, int n_in,
                              void* d_out, int out_size, void* d_ws, size_t ws_size,
                              hipStream_t stream)
{
    const int Bb = 4, T = 2048, E = 512, H = 8;
    const int HE = H * E;            // 4096
    const int N3 = 3 * HE;           // 12288 (merged QKV width)
    const int M  = Bb * T;           // 8192
    const long NX = (long)M * E;     // 4,194,304

    // ---- size-signature input assignment (order-robust) ----
    const void* xr = nullptr;
    const void* Wr[4] = {nullptr, nullptr, nullptr, nullptr};
    const void* br[3] = {nullptr, nullptr, nullptr};
    const void* bor = nullptr;
    int nw = 0, nb = 0;
    for (int i = 0; i < n_in; ++i) {
        int s = in_sizes[i];
        if      (s == (int)NX)      xr = d_in[i];
        else if (s == E * HE)       { if (nw < 4) Wr[nw++] = d_in[i]; }
        else if (s == HE)           { if (nb < 3) br[nb++] = d_in[i]; }
        else if (s == E)            bor = d_in[i];
    }
    if (!xr || nw < 4 || nb < 3 || !bor) {
        xr = d_in[0]; Wr[0] = d_in[1]; br[0] = d_in[2]; Wr[1] = d_in[3];
        br[1] = d_in[4]; Wr[2] = d_in[5]; br[2] = d_in[6]; Wr[3] = d_in[7];
        bor = d_in[8];
    }

    const float qscale = 0.04419417382415922f;  // 1/sqrt(512)
    const int   QC = 1 << 30;                   // "scale all cols"
    dim3 blk(256);

    // ---- workspace layout (bf16 elements) ----
    bf16* pool = (bf16*)d_ws;
    int*  flag = (int*)(void*)pool;
    bf16* xc   = pool + 8;
    bf16* bqc  = xc  + NX;     // bq,bk,bv contiguous -> stacked bias [12288]
    bf16* bkc  = bqc + HE;
    bf16* bvc  = bkc + HE;
    bf16* boc  = bvc + HE;
    bf16* WqT  = boc + E;      // WqT,WkT,WvT contiguous -> stacked Bt [12288,512]
    const size_t w2m = (size_t)E * HE;
    bf16* WkT  = WqT + w2m;
    bf16* WvT  = WkT + w2m;
    bf16* WoT  = WvT + w2m;
    bf16* Ofin = WoT + w2m;
    bf16* p0   = Ofin + NX;

    const size_t wsE    = ws_size / sizeof(bf16);
    const size_t fixedE = (size_t)(p0 - pool);
    const size_t wQKV  = (size_t)T * N3;      // 25.17M el — per-batch QKV
    const size_t wBat  = (size_t)T * HE;      // 8.39M el
    const size_t wHd   = (size_t)T * E;       // 1.05M el
    const size_t sAll  = (size_t)H * T * T;   // 33.55M el
    const size_t sOne  = (size_t)T * T;       // 4.19M el
    const size_t wBig  = (size_t)M * HE;      // 33.55M el
    const size_t needB2 = fixedE + wQKV + wBat + sAll + wBig;  // ~235 MB
    const size_t needB  = fixedE + wQKV + 2 * wBat + sAll;     // ~185 MB (== old)
    const size_t needC  = fixedE + 5 * wBat + sOne;
    const size_t needD  = fixedE + 5 * wHd  + sOne;
    if (wsE < needD) return;

    // ---- stage 0: dtype probe + canonicalize ----
    probe_dtype<<<dim3(1), blk, 0, stream>>>((const float*)xr, flag);
    convert_to_bf16<<<dim3((unsigned)((NX / 8 + 255) / 256)), blk, 0, stream>>>(
        xr, xc, NX, flag);
    convert_to_bf16<<<dim3(2), blk, 0, stream>>>(br[0], bqc, HE, flag);
    convert_to_bf16<<<dim3(2), blk, 0, stream>>>(br[1], bkc, HE, flag);
    convert_to_bf16<<<dim3(2), blk, 0, stream>>>(br[2], bvc, HE, flag);
    convert_to_bf16<<<dim3(1), blk, 0, stream>>>(bor, boc, E, flag);
    transpose_any<<<dim3(HE / 64, E / 64, 1), blk, 0, stream>>>(Wr[0], WqT, HE, E, flag);
    transpose_any<<<dim3(HE / 64, E / 64, 1), blk, 0, stream>>>(Wr[1], WkT, HE, E, flag);
    transpose_any<<<dim3(HE / 64, E / 64, 1), blk, 0, stream>>>(Wr[2], WvT, HE, E, flag);
    transpose_any<<<dim3(E / 64, HE / 64, 1), blk, 0, stream>>>(Wr[3], WoT, E, HE, flag);

    if (wsE >= needB) {
        // ---- Tier B2/B: merged QKV projection; per-batch attention ----
        const bool b2 = (wsE >= needB2);
        bf16* QKVb = p0;                 // [t, 12288] = Q|K|V interleaved
        bf16* Vtb  = QKVb + wQKV;        // [h,e,t]
        bf16* S;                         // [h,t,s]
        bf16* Oatt;                      // attention output
        long  OattStride;                // per-batch stride, ldc = HE
        if (b2) {
            S    = Vtb + wBat;
            Oatt = S + sAll;             // O_all [M, HE]
            OattStride = (long)T * HE;
        } else {
            Oatt = Vtb + wBat;           // Ob [T, HE], reused per batch
            S    = Oatt + wBat;
            OattStride = 0;
        }

        for (int b = 0; b < Bb; ++b) {
            const bf16* xb = xc + (size_t)b * T * E;
            // one GEMM: [t,512] x [12288,512]^T -> Q|K|V, qscale on Q cols
            gemm_bt<<<dim3(N3 / 128, T / 128, 1), blk, 0, stream>>>(
                xb, WqT, QKVb, bqc, E, E, N3, 0, 0, 0, E, qscale, HE, 0);
            // V slice [t, 8192+h*512+e] -> Vt [h,e,t]
            transpose_bf16<<<dim3(E / 64, T / 64, H), blk, 0, stream>>>(
                QKVb + 2 * HE, Vtb, N3, T, H, (long)E, (long)E * T, 0, 0);
            // S[h] = Q[h] @ K[h]^T
            gemm_bt<<<dim3(T / 128, T / 128, H), blk, 0, stream>>>(
                QKVb, QKVb + HE, S, nullptr, N3, N3, T,
                (long)E, (long)E, (long)T * T, E, 1.f, QC, 0);
            softmax_rows2048<<<dim3(H * T, 1, 1), blk, 0, stream>>>(S);
            // O[t, h*E+e] = P[h] @ Vt[h]^T
            gemm_bt<<<dim3(E / 128, T / 128, H), blk, 0, stream>>>(
                S, Vtb, Oatt + (size_t)b * OattStride, nullptr, T, T, HE,
                (long)T * T, (long)E * T, (long)E, T, 1.f, QC, 0);
            if (!b2) {
                // per-batch out-proj: split-K=8, fp32 partials alias S
                gemm_bt_splitk<<<dim3(E / 128, T / 128, 8), blk, 0, stream>>>(
                    Oatt, WoT, (float*)S, HE, HE, T, E, HE / 8);
                reduce_splitk<<<dim3((unsigned)(((long)T * E + 255) / 256)), blk, 0, stream>>>(
                    (float*)S, boc, Ofin + (size_t)b * T * E, (long)T * E, E, 8);
            }
        }
        if (b2) {
            // all-batch out-proj: split-K=4, fp32 partials alias QKVb+Vtb
            // (exactly 67.1 MB; both dead by now)
            gemm_bt_splitk<<<dim3(E / 128, M / 128, 4), blk, 0, stream>>>(
                Oatt, WoT, (float*)QKVb, HE, HE, M, E, HE / 4);
            reduce_splitk<<<dim3((unsigned)((NX + 255) / 256)), blk, 0, stream>>>(
                (float*)QKVb, boc, Ofin, NX, E, 4);
        }
    } else if (wsE >= needC) {
        // ---- Tier C: per-batch, per-head S (unchanged from round 5) ----
        bf16* Qb  = p0;
        bf16* Kb  = Qb  + wBat;
        bf16* Vb  = Kb  + wBat;
        bf16* Vtb = Vb  + wBat;
        bf16* Ob  = Vtb + wBat;
        bf16* S   = Ob  + wBat;

        for (int b = 0; b < Bb; ++b) {
            const bf16* xb = xc + (size_t)b * T * E;
            gemm_bt<<<dim3(HE / 128, T / 128, 1), blk, 0, stream>>>(
                xb, WqT, Qb, bqc, E, E, HE, 0, 0, 0, E, qscale, QC, 0);
            gemm_bt<<<dim3(HE / 128, T / 128, 1), blk, 0, stream>>>(
                xb, WkT, Kb, bkc, E, E, HE, 0, 0, 0, E, 1.f, QC, 0);
            gemm_bt<<<dim3(HE / 128, T / 128, 1), blk, 0, stream>>>(
                xb, WvT, Vb, bvc, E, E, HE, 0, 0, 0, E, 1.f, QC, 0);
            transpose_bf16<<<dim3(E / 64, T / 64, H), blk, 0, stream>>>(
                Vb, Vtb, HE, T, H, (long)E, (long)E * T, 0, 0);
            for (int h = 0; h < H; ++h) {
                gemm_bt<<<dim3(T / 128, T / 128, 1), blk, 0, stream>>>(
                    Qb + (size_t)h * E, Kb + (size_t)h * E, S, nullptr,
                    HE, HE, T, 0, 0, 0, E, 1.f, QC, 0);
                softmax_rows2048<<<dim3(T, 1, 1), blk, 0, stream>>>(S);
                gemm_bt<<<dim3(E / 128, T / 128, 1), blk, 0, stream>>>(
                    S, Vtb + (size_t)h * E * T, Ob + (size_t)h * E, nullptr,
                    T, T, HE, 0, 0, 0, T, 1.f, QC, 0);
            }
            gemm_bt<<<dim3(E / 128, T / 128, 1), blk, 0, stream>>>(
                Ob, WoT, Ofin + (size_t)b * T * E, boc,
                HE, HE, E, 0, 0, 0, HE, 1.f, QC, 0);
        }
    } else {
        // ---- Tier D: per-(batch,head); out-proj accumulates ----
        bf16* Qh  = p0;
        bf16* Kh  = Qh  + wHd;
        bf16* Vh  = Kh  + wHd;
        bf16* Vth = Vh  + wHd;
        bf16* Oh  = Vth + wHd;
        bf16* S   = Oh  + wHd;

        for (int b = 0; b < Bb; ++b) {
            const bf16* xb = xc + (size_t)b * T * E;
            bf16* outb = Ofin + (size_t)b * T * E;
            for (int h = 0; h < H; ++h) {
                const size_t hw = (size_t)h * E * E;
                gemm_bt<<<dim3(E / 128, T / 128, 1), blk, 0, stream>>>(
                    xb, WqT + hw, Qh, bqc + (size_t)h * E, E, E, E,
                    0, 0, 0, E, qscale, QC, 0);
                gemm_bt<<<dim3(E / 128, T / 128, 1), blk, 0, stream>>>(
                    xb, WkT + hw, Kh, bkc + (size_t)h * E, E, E, E,
                    0, 0, 0, E, 1.f, QC, 0);
                gemm_bt<<<dim3(E / 128, T / 128, 1), blk, 0, stream>>>(
                    xb, WvT + hw, Vh, bvc + (size_t)h * E, E, E, E,
                    0, 0, 0, E, 1.f, QC, 0);
                transpose_bf16<<<dim3(E / 64, T / 64, 1), blk, 0, stream>>>(
                    Vh, Vth, E, T, 1, 0, 0, 0, 0);
                gemm_bt<<<dim3(T / 128, T / 128, 1), blk, 0, stream>>>(
                    Qh, Kh, S, nullptr, E, E, T, 0, 0, 0, E, 1.f, QC, 0);
                softmax_rows2048<<<dim3(T, 1, 1), blk, 0, stream>>>(S);
                gemm_bt<<<dim3(E / 128, T / 128, 1), blk, 0, stream>>>(
                    S, Vth, Oh, nullptr, T, T, E, 0, 0, 0, T, 1.f, QC, 0);
                gemm_bt<<<dim3(E / 128, T / 128, 1), blk, 0, stream>>>(
                    Oh, WoT + (size_t)h * E, outb, (h == 0) ? boc : nullptr,
                    E, HE, E, 0, 0, 0, E, 1.f, QC, (h == 0) ? 0 : 1);
            }
        }
    }

    // ---- emit in the probed dtype ----
    emit_out<<<dim3((unsigned)((NX / 8 + 255) / 256)), blk, 0, stream>>>(
        Ofin, d_out, NX, flag);
}